// Round 1
// 2327.693 us; speedup vs baseline: 1.1196x; 1.1196x over previous
//
#include <hip/hip_runtime.h>
#include <hip/hip_bf16.h>

#define NU_ 50000
#define NI_ 50000
#define NN  (NU_ + NI_)   // 100000
#define DD  64
#define KK  4
#define EE  1000000
#define SCAN_B ((NN + 255) / 256)   // 391

#define P_RANGES 8
#define RANGE_SZ ((NN + P_RANGES - 1) / P_RANGES)  // 12500

// ---------- histogram of node degrees (int counts) ----------
__global__ void k_hist(const int* __restrict__ r, const int* __restrict__ c,
                       int* __restrict__ cnt) {
    int e = blockIdx.x * blockDim.x + threadIdx.x;
    if (e >= EE) return;
    int a = r[e], b = c[e];
    if ((unsigned)a >= (unsigned)NU_ || (unsigned)b >= (unsigned)NI_) return; // defensive
    atomicAdd(&cnt[a], 1);
    atomicAdd(&cnt[NU_ + b], 1);
}

// ---------- pass 1: per-block sums of cnt ----------
__global__ __launch_bounds__(256) void k_bsum(const int* __restrict__ cnt,
                                              int* __restrict__ bsum) {
    __shared__ int s[256];
    int i = blockIdx.x * 256 + threadIdx.x;
    s[threadIdx.x] = (i < NN) ? cnt[i] : 0;
    __syncthreads();
    #pragma unroll
    for (int off = 128; off > 0; off >>= 1) {
        if (threadIdx.x < off) s[threadIdx.x] += s[threadIdx.x + off];
        __syncthreads();
    }
    if (threadIdx.x == 0) bsum[blockIdx.x] = s[0];
}

// ---------- pass 2: scan 391 block sums (one small block) ----------
__global__ __launch_bounds__(512) void k_sscan(const int* __restrict__ bsum,
                                               int* __restrict__ bofs) {
    __shared__ int s[512];
    int tid = threadIdx.x;
    s[tid] = (tid < SCAN_B) ? bsum[tid] : 0;
    __syncthreads();
    #pragma unroll
    for (int off = 1; off < 512; off <<= 1) {
        int v = (tid >= off) ? s[tid - off] : 0;
        __syncthreads();
        s[tid] += v;
        __syncthreads();
    }
    if (tid < SCAN_B) bofs[tid] = (tid > 0) ? s[tid - 1] : 0;
}

// ---------- pass 3: intra-block scan + offset -> row_ptr/cursor/dinv ----------
__global__ __launch_bounds__(256) void k_apply(const int* __restrict__ cnt,
                                               const int* __restrict__ bofs,
                                               int* __restrict__ row_ptr,
                                               int* __restrict__ cursor,
                                               float* __restrict__ dinv) {
    __shared__ int s[256];
    int i = blockIdx.x * 256 + threadIdx.x;
    int v = (i < NN) ? cnt[i] : 0;
    s[threadIdx.x] = v;
    __syncthreads();
    #pragma unroll
    for (int off = 1; off < 256; off <<= 1) {
        int t = (threadIdx.x >= off) ? s[threadIdx.x - off] : 0;
        __syncthreads();
        s[threadIdx.x] += t;
        __syncthreads();
    }
    if (i < NN) {
        int incl = s[threadIdx.x] + bofs[blockIdx.x];
        int excl = incl - v;
        row_ptr[i] = excl;
        cursor[i] = excl;
        dinv[i] = rsqrtf((float)v + 1e-7f);
        if (i == NN - 1) row_ptr[NN] = incl;
    }
}

// ---------- XCD-range-partitioned scatter into CSR adjacency ----------
// Group g = blockIdx.x (intended XCD via bid%8 round-robin) scans ALL edges
// but only writes rows in [g*RANGE_SZ, (g+1)*RANGE_SZ). Each adj line (16
// entries) then accumulates ALL its writes inside ONE XCD's L2 -> one 64B
// writeback per line instead of one per 4B entry (was 127.5 MB WRITE_SIZE).
// Correct for ANY blockIdx->XCD mapping: every (edge,side) is written by
// exactly one group; a wrong mapping only costs speed.
__global__ __launch_bounds__(256) void k_scatter2(const int* __restrict__ r,
                                                  const int* __restrict__ c,
                                                  int* __restrict__ cursor,
                                                  int* __restrict__ adj) {
    const int g = blockIdx.x;                 // 0..7
    const int lo = g * RANGE_SZ;
    int e = blockIdx.y * 256 + threadIdx.x;
    if (e >= EE) return;
    int a = r[e], b = c[e];
    if ((unsigned)a >= (unsigned)NU_ || (unsigned)b >= (unsigned)NI_) return; // defensive
    b += NU_;
    if ((unsigned)(a - lo) < (unsigned)RANGE_SZ) {
        int p = atomicAdd(&cursor[a], 1);
        adj[p] = b;
    }
    if ((unsigned)(b - lo) < (unsigned)RANGE_SZ) {
        int q = atomicAdd(&cursor[b], 1);
        adj[q] = a;
    }
}

// ---------- pull SpMM with fused h = relu(x)+bias on the gathered operand ----------
// out[row] = dinv[row] * sum_nbr dinv[nbr] * (relu(x[nbr]) + bias)
__global__ __launch_bounds__(256) void k_pull_h(const int* __restrict__ row_ptr,
                                                const int* __restrict__ adj,
                                                const float* __restrict__ dinv,
                                                const float* __restrict__ x,
                                                const float* __restrict__ bias,
                                                float* __restrict__ out) {
    const int wave = threadIdx.x >> 6;
    const int lane = threadIdx.x & 63;
    const int row = blockIdx.x * 4 + wave;
    if (row >= NN) return;
    const float bv = bias[lane];
    const int start = row_ptr[row];
    const int end = row_ptr[row + 1];
    float acc = 0.0f;
    for (int base = start; base < end; base += 64) {
        int n = end - base; if (n > 64) n = 64;
        int idx = (lane < n) ? adj[base + lane] : 0;
        float dn = (lane < n) ? dinv[idx] : 0.0f;
        #pragma unroll 4
        for (int j = 0; j < n; j++) {
            int nbr = __shfl(idx, j);
            float w = __shfl(dn, j);
            float xv = x[(size_t)nbr * DD + lane];
            acc = fmaf(w, fmaxf(xv, 0.0f) + bv, acc);
        }
    }
    out[(size_t)row * DD + lane] = dinv[row] * acc;
}

// ---------- plain pull SpMM ----------
__global__ __launch_bounds__(256) void k_pull(const int* __restrict__ row_ptr,
                                              const int* __restrict__ adj,
                                              const float* __restrict__ dinv,
                                              const float* __restrict__ hin,
                                              float* __restrict__ out) {
    const int wave = threadIdx.x >> 6;
    const int lane = threadIdx.x & 63;
    const int row = blockIdx.x * 4 + wave;
    if (row >= NN) return;
    const int start = row_ptr[row];
    const int end = row_ptr[row + 1];
    float acc = 0.0f;
    for (int base = start; base < end; base += 64) {
        int n = end - base; if (n > 64) n = 64;
        int idx = (lane < n) ? adj[base + lane] : 0;
        float dn = (lane < n) ? dinv[idx] : 0.0f;
        #pragma unroll 4
        for (int j = 0; j < n; j++) {
            int nbr = __shfl(idx, j);
            float w = __shfl(dn, j);
            acc = fmaf(w, hin[(size_t)nbr * DD + lane], acc);
        }
    }
    out[(size_t)row * DD + lane] = dinv[row] * acc;
}

// ---------- fused: softmax(node) -> fc1 -> fusion gate -> x_new ----------
// NO LDS: lane j holds fc1W[j][:] and fusW[j][:] in VGPRs; broadcasts via
// v_readlane (VALU pipe). Runs IN PLACE (node may alias out_nodes).
#define BC(v, d) __uint_as_float(__builtin_amdgcn_readlane(__float_as_uint(v), (d)))

__global__ __launch_bounds__(256) void k_row(
    const float* __restrict__ node, const float* __restrict__ xsrc,
    const float* __restrict__ fc1W, const float* __restrict__ fusW,
    const float* __restrict__ l1b, const float* __restrict__ l2w,
    const float* __restrict__ l2b, float* __restrict__ out_nodes) {
    const int wave = threadIdx.x >> 6;
    const int lane = threadIdx.x & 63;

    float wf[DD], wu[DD];
    #pragma unroll
    for (int d = 0; d < DD; d += 4) {
        *(float4*)&wf[d] = *(const float4*)&fc1W[(size_t)lane * DD + d];
        *(float4*)&wu[d] = *(const float4*)&fusW[(size_t)lane * DD + d];
    }
    const float b1v = l1b[lane];
    const float l2v = l2w[lane];
    const float b2v = l2b[0];

    for (int row = blockIdx.x * 4 + wave; row < NN; row += gridDim.x * 4) {
        const size_t base = (size_t)row * DD + lane;
        float v = node[base];
        // --- softmax over D=64 ---
        float m = v;
        #pragma unroll
        for (int s = 1; s < 64; s <<= 1) m = fmaxf(m, __shfl_xor(m, s));
        float ev = __expf(v - m);
        float sum = ev;
        #pragma unroll
        for (int s = 1; s < 64; s <<= 1) sum += __shfl_xor(sum, s);
        float sm = ev / sum;
        // --- fc1 ---
        float n0 = 0, n1 = 0, n2 = 0, n3 = 0;
        #pragma unroll
        for (int d = 0; d < DD; d += 4) {
            n0 = fmaf(BC(sm, d),     wf[d],     n0);
            n1 = fmaf(BC(sm, d + 1), wf[d + 1], n1);
            n2 = fmaf(BC(sm, d + 2), wf[d + 2], n2);
            n3 = fmaf(BC(sm, d + 3), wf[d + 3], n3);
        }
        float nf = (n0 + n1) + (n2 + n3);
        float xc = xsrc[base];
        // --- fusion branch: xc ---
        float a0 = 0, a1 = 0, a2 = 0, a3 = 0;
        #pragma unroll
        for (int d = 0; d < DD; d += 4) {
            a0 = fmaf(BC(xc, d),     wu[d],     a0);
            a1 = fmaf(BC(xc, d + 1), wu[d + 1], a1);
            a2 = fmaf(BC(xc, d + 2), wu[d + 2], a2);
            a3 = fmaf(BC(xc, d + 3), wu[d + 3], a3);
        }
        float tt = tanhf(((a0 + a1) + (a2 + a3)) + b1v);
        float p = tt * l2v;
        #pragma unroll
        for (int s = 1; s < 64; s <<= 1) p += __shfl_xor(p, s);
        float s_x = p + b2v;
        // --- fusion branch: nf ---
        a0 = 0; a1 = 0; a2 = 0; a3 = 0;
        #pragma unroll
        for (int d = 0; d < DD; d += 4) {
            a0 = fmaf(BC(nf, d),     wu[d],     a0);
            a1 = fmaf(BC(nf, d + 1), wu[d + 1], a1);
            a2 = fmaf(BC(nf, d + 2), wu[d + 2], a2);
            a3 = fmaf(BC(nf, d + 3), wu[d + 3], a3);
        }
        tt = tanhf(((a0 + a1) + (a2 + a3)) + b1v);
        p = tt * l2v;
        #pragma unroll
        for (int s = 1; s < 64; s <<= 1) p += __shfl_xor(p, s);
        float s_n = p + b2v;
        // --- gate + blend ---
        float mm = fmaxf(s_x, s_n);
        float e0 = __expf(s_x - mm), e1 = __expf(s_n - mm);
        float inv = 1.0f / (e0 + e1);
        float xn = (e0 * xc + e1 * nf) * inv;
        out_nodes[base] = xn;
    }
}

extern "C" void kernel_launch(void* const* d_in, const int* in_sizes, int n_in,
                              void* d_out, int out_size, void* d_ws, size_t ws_size,
                              hipStream_t stream) {
    const float* x    = (const float*)d_in[0];
    const float* b1   = (const float*)d_in[1];  // hgc1_bias
    const float* fc1W = (const float*)d_in[2];
    const float* fusW = (const float*)d_in[3];  // fus_l1_W
    const float* l1b  = (const float*)d_in[4];
    const float* l2w  = (const float*)d_in[5];
    const float* l2b  = (const float*)d_in[6];
    const int* rows = (const int*)d_in[7];
    const int* cols = (const int*)d_in[8];
    float* out = (float*)d_out;

    const int ND = NN * DD;  // 6,400,000

    // workspace layout (~9.7 MB)
    float* dinv    = (float*)d_ws;           // NN
    int*   cnt     = (int*)(dinv + NN);      // NN
    int*   row_ptr = cnt + NN;               // NN+1
    int*   cursor  = row_ptr + NN + 1;       // NN
    int*   bsum    = cursor + NN;            // SCAN_B
    int*   bofs    = bsum + SCAN_B;          // SCAN_B
    int*   adj     = bofs + SCAN_B;          // 2*EE

    for (int k = 0; k < KK; k++) {
        const int* r = rows + (size_t)k * EE;
        const int* c = cols + (size_t)k * EE;
        const float* xk = (k == 0) ? x : out + (size_t)(k - 1) * ND;  // carry
        float* out_n = out + (size_t)k * ND;         // nodes[k] slot
        float* out_e = out + (size_t)(KK + k) * ND;  // edges[k] slot

        // --- CSR build (parallel scan) ---
        hipMemsetAsync(cnt, 0, NN * sizeof(int), stream);
        k_hist<<<(EE + 255) / 256, 256, 0, stream>>>(r, c, cnt);
        k_bsum<<<SCAN_B, 256, 0, stream>>>(cnt, bsum);
        k_sscan<<<1, 512, 0, stream>>>(bsum, bofs);
        k_apply<<<SCAN_B, 256, 0, stream>>>(cnt, bofs, row_ptr, cursor, dinv);
        {
            dim3 g(P_RANGES, (EE + 255) / 256);
            k_scatter2<<<g, 256, 0, stream>>>(r, c, cursor, adj);
        }

        // edge = L (relu(xk)+bias)   (fused h, direct store into edges[k])
        k_pull_h<<<(NN + 3) / 4, 256, 0, stream>>>(row_ptr, adj, dinv, xk, b1, out_e);

        // node = L edge  (into nodes[k] slot)
        k_pull<<<(NN + 3) / 4, 256, 0, stream>>>(row_ptr, adj, dinv, out_e, out_n);

        // softmax -> fc1 -> fusion gate; x_new in place into nodes[k]
        k_row<<<1024, 256, 0, stream>>>(out_n, xk, fc1W, fusW, l1b, l2w, l2b, out_n);
    }
}

// Round 2
// 1905.348 us; speedup vs baseline: 1.3678x; 1.2217x over previous
//
#include <hip/hip_runtime.h>
#include <hip/hip_bf16.h>

#define NU_ 50000
#define NI_ 50000
#define NN  (NU_ + NI_)   // 100000
#define DD  64
#define KK  4
#define EE  1000000
#define SCAN_B ((NN + 255) / 256)   // 391

#define P_RANGES 8
#define RANGE_SZ ((NN + P_RANGES - 1) / P_RANGES)  // 12500

// ---------- histogram of node degrees (int counts) ----------
__global__ void k_hist(const int* __restrict__ r, const int* __restrict__ c,
                       int* __restrict__ cnt) {
    int e = blockIdx.x * blockDim.x + threadIdx.x;
    if (e >= EE) return;
    int a = r[e], b = c[e];
    if ((unsigned)a >= (unsigned)NU_ || (unsigned)b >= (unsigned)NI_) return; // defensive
    atomicAdd(&cnt[a], 1);
    atomicAdd(&cnt[NU_ + b], 1);
}

// ---------- pass 1: per-block sums of cnt ----------
__global__ __launch_bounds__(256) void k_bsum(const int* __restrict__ cnt,
                                              int* __restrict__ bsum) {
    __shared__ int s[256];
    int i = blockIdx.x * 256 + threadIdx.x;
    s[threadIdx.x] = (i < NN) ? cnt[i] : 0;
    __syncthreads();
    #pragma unroll
    for (int off = 128; off > 0; off >>= 1) {
        if (threadIdx.x < off) s[threadIdx.x] += s[threadIdx.x + off];
        __syncthreads();
    }
    if (threadIdx.x == 0) bsum[blockIdx.x] = s[0];
}

// ---------- pass 2: scan 391 block sums (one small block) ----------
__global__ __launch_bounds__(512) void k_sscan(const int* __restrict__ bsum,
                                               int* __restrict__ bofs) {
    __shared__ int s[512];
    int tid = threadIdx.x;
    s[tid] = (tid < SCAN_B) ? bsum[tid] : 0;
    __syncthreads();
    #pragma unroll
    for (int off = 1; off < 512; off <<= 1) {
        int v = (tid >= off) ? s[tid - off] : 0;
        __syncthreads();
        s[tid] += v;
        __syncthreads();
    }
    if (tid < SCAN_B) bofs[tid] = (tid > 0) ? s[tid - 1] : 0;
}

// ---------- pass 3: intra-block scan + offset -> row_ptr/cursor/dinv ----------
__global__ __launch_bounds__(256) void k_apply(const int* __restrict__ cnt,
                                               const int* __restrict__ bofs,
                                               int* __restrict__ row_ptr,
                                               int* __restrict__ cursor,
                                               float* __restrict__ dinv) {
    __shared__ int s[256];
    int i = blockIdx.x * 256 + threadIdx.x;
    int v = (i < NN) ? cnt[i] : 0;
    s[threadIdx.x] = v;
    __syncthreads();
    #pragma unroll
    for (int off = 1; off < 256; off <<= 1) {
        int t = (threadIdx.x >= off) ? s[threadIdx.x - off] : 0;
        __syncthreads();
        s[threadIdx.x] += t;
        __syncthreads();
    }
    if (i < NN) {
        int incl = s[threadIdx.x] + bofs[blockIdx.x];
        int excl = incl - v;
        row_ptr[i] = excl;
        cursor[i] = excl;
        dinv[i] = rsqrtf((float)v + 1e-7f);
        if (i == NN - 1) row_ptr[NN] = incl;
    }
}

// ---------- XCD-range-partitioned scatter into CSR adjacency ----------
// Group g = blockIdx.x (intended XCD via bid%8 round-robin) scans ALL edges
// but only writes rows in [g*RANGE_SZ, (g+1)*RANGE_SZ). Each adj line (16
// entries) then accumulates ALL its writes inside ONE XCD's L2 -> one 64B
// writeback per line instead of one per 4B entry. (R0: WRITE_SIZE 127.5MB
// -> gone from top-5; total -278us.)
__global__ __launch_bounds__(256) void k_scatter2(const int* __restrict__ r,
                                                  const int* __restrict__ c,
                                                  int* __restrict__ cursor,
                                                  int* __restrict__ adj) {
    const int g = blockIdx.x;                 // 0..7
    const int lo = g * RANGE_SZ;
    int e = blockIdx.y * 256 + threadIdx.x;
    if (e >= EE) return;
    int a = r[e], b = c[e];
    if ((unsigned)a >= (unsigned)NU_ || (unsigned)b >= (unsigned)NI_) return; // defensive
    b += NU_;
    if ((unsigned)(a - lo) < (unsigned)RANGE_SZ) {
        int p = atomicAdd(&cursor[a], 1);
        adj[p] = b;
    }
    if ((unsigned)(b - lo) < (unsigned)RANGE_SZ) {
        int q = atomicAdd(&cursor[b], 1);
        adj[q] = a;
    }
}

// ---------- pull SpMM, quarter-wave (16 lanes) per row, float4 per lane ----------
// R1 restructure: one row per QUARTER-wave -> 4 independent gather chains per
// wave, 16B/lane loads (global_load_dwordx4). Same traffic, 4x the
// memory-level parallelism (latency-bound per R1 counters: 3.9 TB/s L2-side
// << 34.5 ceiling, VALUBusy 27%).
// out[row] = dinv[row] * sum_nbr dinv[nbr] * (relu(x[nbr]) + bias)
__global__ __launch_bounds__(256) void k_pull_h(const int* __restrict__ row_ptr,
                                                const int* __restrict__ adj,
                                                const float* __restrict__ dinv,
                                                const float* __restrict__ x,
                                                const float* __restrict__ bias,
                                                float* __restrict__ out) {
    const int wave = threadIdx.x >> 6;
    const int lane = threadIdx.x & 63;
    const int sub  = lane >> 4;       // quarter id 0..3
    const int l16  = lane & 15;
    const int row  = (blockIdx.x * 4 + wave) * 4 + sub;  // NN%16==0: no tail
    const float4 bv = *(const float4*)&bias[l16 * 4];
    const int start = row_ptr[row];
    const int end   = row_ptr[row + 1];
    float4 acc = {0.f, 0.f, 0.f, 0.f};
    for (int base = start; base < end; base += 16) {
        int n = end - base; if (n > 16) n = 16;
        int idx  = (l16 < n) ? adj[base + l16] : 0;
        float dn = (l16 < n) ? dinv[idx] : 0.0f;
        #pragma unroll 4
        for (int j = 0; j < n; j++) {
            int   nbr = __shfl(idx, (sub << 4) + j);   // broadcast within quarter
            float w   = __shfl(dn,  (sub << 4) + j);
            const float4 xv = *(const float4*)&x[(size_t)nbr * DD + l16 * 4];
            acc.x = fmaf(w, fmaxf(xv.x, 0.f) + bv.x, acc.x);
            acc.y = fmaf(w, fmaxf(xv.y, 0.f) + bv.y, acc.y);
            acc.z = fmaf(w, fmaxf(xv.z, 0.f) + bv.z, acc.z);
            acc.w = fmaf(w, fmaxf(xv.w, 0.f) + bv.w, acc.w);
        }
    }
    const float dr = dinv[row];
    float4 o = {dr * acc.x, dr * acc.y, dr * acc.z, dr * acc.w};
    *(float4*)&out[(size_t)row * DD + l16 * 4] = o;
}

// ---------- plain pull SpMM (same quarter-wave structure) ----------
__global__ __launch_bounds__(256) void k_pull(const int* __restrict__ row_ptr,
                                              const int* __restrict__ adj,
                                              const float* __restrict__ dinv,
                                              const float* __restrict__ hin,
                                              float* __restrict__ out) {
    const int wave = threadIdx.x >> 6;
    const int lane = threadIdx.x & 63;
    const int sub  = lane >> 4;
    const int l16  = lane & 15;
    const int row  = (blockIdx.x * 4 + wave) * 4 + sub;
    const int start = row_ptr[row];
    const int end   = row_ptr[row + 1];
    float4 acc = {0.f, 0.f, 0.f, 0.f};
    for (int base = start; base < end; base += 16) {
        int n = end - base; if (n > 16) n = 16;
        int idx  = (l16 < n) ? adj[base + l16] : 0;
        float dn = (l16 < n) ? dinv[idx] : 0.0f;
        #pragma unroll 4
        for (int j = 0; j < n; j++) {
            int   nbr = __shfl(idx, (sub << 4) + j);
            float w   = __shfl(dn,  (sub << 4) + j);
            const float4 hv = *(const float4*)&hin[(size_t)nbr * DD + l16 * 4];
            acc.x = fmaf(w, hv.x, acc.x);
            acc.y = fmaf(w, hv.y, acc.y);
            acc.z = fmaf(w, hv.z, acc.z);
            acc.w = fmaf(w, hv.w, acc.w);
        }
    }
    const float dr = dinv[row];
    float4 o = {dr * acc.x, dr * acc.y, dr * acc.z, dr * acc.w};
    *(float4*)&out[(size_t)row * DD + l16 * 4] = o;
}

// ---------- fused: softmax(node) -> fc1 -> fusion gate -> x_new ----------
// NO LDS: lane j holds fc1W[j][:] and fusW[j][:] in VGPRs; broadcasts via
// v_readlane (VALU pipe). Runs IN PLACE (node may alias out_nodes).
#define BC(v, d) __uint_as_float(__builtin_amdgcn_readlane(__float_as_uint(v), (d)))

__global__ __launch_bounds__(256) void k_row(
    const float* __restrict__ node, const float* __restrict__ xsrc,
    const float* __restrict__ fc1W, const float* __restrict__ fusW,
    const float* __restrict__ l1b, const float* __restrict__ l2w,
    const float* __restrict__ l2b, float* __restrict__ out_nodes) {
    const int wave = threadIdx.x >> 6;
    const int lane = threadIdx.x & 63;

    float wf[DD], wu[DD];
    #pragma unroll
    for (int d = 0; d < DD; d += 4) {
        *(float4*)&wf[d] = *(const float4*)&fc1W[(size_t)lane * DD + d];
        *(float4*)&wu[d] = *(const float4*)&fusW[(size_t)lane * DD + d];
    }
    const float b1v = l1b[lane];
    const float l2v = l2w[lane];
    const float b2v = l2b[0];

    for (int row = blockIdx.x * 4 + wave; row < NN; row += gridDim.x * 4) {
        const size_t base = (size_t)row * DD + lane;
        float v = node[base];
        // --- softmax over D=64 ---
        float m = v;
        #pragma unroll
        for (int s = 1; s < 64; s <<= 1) m = fmaxf(m, __shfl_xor(m, s));
        float ev = __expf(v - m);
        float sum = ev;
        #pragma unroll
        for (int s = 1; s < 64; s <<= 1) sum += __shfl_xor(sum, s);
        float sm = ev / sum;
        // --- fc1 ---
        float n0 = 0, n1 = 0, n2 = 0, n3 = 0;
        #pragma unroll
        for (int d = 0; d < DD; d += 4) {
            n0 = fmaf(BC(sm, d),     wf[d],     n0);
            n1 = fmaf(BC(sm, d + 1), wf[d + 1], n1);
            n2 = fmaf(BC(sm, d + 2), wf[d + 2], n2);
            n3 = fmaf(BC(sm, d + 3), wf[d + 3], n3);
        }
        float nf = (n0 + n1) + (n2 + n3);
        float xc = xsrc[base];
        // --- fusion branch: xc ---
        float a0 = 0, a1 = 0, a2 = 0, a3 = 0;
        #pragma unroll
        for (int d = 0; d < DD; d += 4) {
            a0 = fmaf(BC(xc, d),     wu[d],     a0);
            a1 = fmaf(BC(xc, d + 1), wu[d + 1], a1);
            a2 = fmaf(BC(xc, d + 2), wu[d + 2], a2);
            a3 = fmaf(BC(xc, d + 3), wu[d + 3], a3);
        }
        float tt = tanhf(((a0 + a1) + (a2 + a3)) + b1v);
        float p = tt * l2v;
        #pragma unroll
        for (int s = 1; s < 64; s <<= 1) p += __shfl_xor(p, s);
        float s_x = p + b2v;
        // --- fusion branch: nf ---
        a0 = 0; a1 = 0; a2 = 0; a3 = 0;
        #pragma unroll
        for (int d = 0; d < DD; d += 4) {
            a0 = fmaf(BC(nf, d),     wu[d],     a0);
            a1 = fmaf(BC(nf, d + 1), wu[d + 1], a1);
            a2 = fmaf(BC(nf, d + 2), wu[d + 2], a2);
            a3 = fmaf(BC(nf, d + 3), wu[d + 3], a3);
        }
        tt = tanhf(((a0 + a1) + (a2 + a3)) + b1v);
        p = tt * l2v;
        #pragma unroll
        for (int s = 1; s < 64; s <<= 1) p += __shfl_xor(p, s);
        float s_n = p + b2v;
        // --- gate + blend ---
        float mm = fmaxf(s_x, s_n);
        float e0 = __expf(s_x - mm), e1 = __expf(s_n - mm);
        float inv = 1.0f / (e0 + e1);
        float xn = (e0 * xc + e1 * nf) * inv;
        out_nodes[base] = xn;
    }
}

extern "C" void kernel_launch(void* const* d_in, const int* in_sizes, int n_in,
                              void* d_out, int out_size, void* d_ws, size_t ws_size,
                              hipStream_t stream) {
    const float* x    = (const float*)d_in[0];
    const float* b1   = (const float*)d_in[1];  // hgc1_bias
    const float* fc1W = (const float*)d_in[2];
    const float* fusW = (const float*)d_in[3];  // fus_l1_W
    const float* l1b  = (const float*)d_in[4];
    const float* l2w  = (const float*)d_in[5];
    const float* l2b  = (const float*)d_in[6];
    const int* rows = (const int*)d_in[7];
    const int* cols = (const int*)d_in[8];
    float* out = (float*)d_out;

    const int ND = NN * DD;  // 6,400,000

    // workspace layout (~9.7 MB)
    float* dinv    = (float*)d_ws;           // NN
    int*   cnt     = (int*)(dinv + NN);      // NN
    int*   row_ptr = cnt + NN;               // NN+1
    int*   cursor  = row_ptr + NN + 1;       // NN
    int*   bsum    = cursor + NN;            // SCAN_B
    int*   bofs    = bsum + SCAN_B;          // SCAN_B
    int*   adj     = bofs + SCAN_B;          // 2*EE

    for (int k = 0; k < KK; k++) {
        const int* r = rows + (size_t)k * EE;
        const int* c = cols + (size_t)k * EE;
        const float* xk = (k == 0) ? x : out + (size_t)(k - 1) * ND;  // carry
        float* out_n = out + (size_t)k * ND;         // nodes[k] slot
        float* out_e = out + (size_t)(KK + k) * ND;  // edges[k] slot

        // --- CSR build (parallel scan) ---
        hipMemsetAsync(cnt, 0, NN * sizeof(int), stream);
        k_hist<<<(EE + 255) / 256, 256, 0, stream>>>(r, c, cnt);
        k_bsum<<<SCAN_B, 256, 0, stream>>>(cnt, bsum);
        k_sscan<<<1, 512, 0, stream>>>(bsum, bofs);
        k_apply<<<SCAN_B, 256, 0, stream>>>(cnt, bofs, row_ptr, cursor, dinv);
        {
            dim3 g(P_RANGES, (EE + 255) / 256);
            k_scatter2<<<g, 256, 0, stream>>>(r, c, cursor, adj);
        }

        // edge = L (relu(xk)+bias)   (fused h, direct store into edges[k])
        // 16 rows per 256-thread block (4 waves x 4 quarter-rows)
        k_pull_h<<<NN / 16, 256, 0, stream>>>(row_ptr, adj, dinv, xk, b1, out_e);

        // node = L edge  (into nodes[k] slot)
        k_pull<<<NN / 16, 256, 0, stream>>>(row_ptr, adj, dinv, out_e, out_n);

        // softmax -> fc1 -> fusion gate; x_new in place into nodes[k]
        k_row<<<1024, 256, 0, stream>>>(out_n, xk, fc1W, fusW, l1b, l2w, l2b, out_n);
    }
}

// Round 3
// 1848.556 us; speedup vs baseline: 1.4098x; 1.0307x over previous
//
#include <hip/hip_runtime.h>
#include <hip/hip_bf16.h>

#define NU_ 50000
#define NI_ 50000
#define NN  (NU_ + NI_)   // 100000
#define DD  64
#define KK  4
#define EE  1000000
#define SCAN_B ((NN + 255) / 256)   // 391

#define P_RANGES 8
#define RANGE_SZ ((NN + P_RANGES - 1) / P_RANGES)  // 12500

// ---------- histogram of node degrees (int counts) ----------
__global__ void k_hist(const int* __restrict__ r, const int* __restrict__ c,
                       int* __restrict__ cnt) {
    int e = blockIdx.x * blockDim.x + threadIdx.x;
    if (e >= EE) return;
    int a = r[e], b = c[e];
    if ((unsigned)a >= (unsigned)NU_ || (unsigned)b >= (unsigned)NI_) return; // defensive
    atomicAdd(&cnt[a], 1);
    atomicAdd(&cnt[NU_ + b], 1);
}

// ---------- pass 1: per-block sums of cnt ----------
__global__ __launch_bounds__(256) void k_bsum(const int* __restrict__ cnt,
                                              int* __restrict__ bsum) {
    __shared__ int s[256];
    int i = blockIdx.x * 256 + threadIdx.x;
    s[threadIdx.x] = (i < NN) ? cnt[i] : 0;
    __syncthreads();
    #pragma unroll
    for (int off = 128; off > 0; off >>= 1) {
        if (threadIdx.x < off) s[threadIdx.x] += s[threadIdx.x + off];
        __syncthreads();
    }
    if (threadIdx.x == 0) bsum[blockIdx.x] = s[0];
}

// ---------- pass 2: scan 391 block sums (one small block) ----------
__global__ __launch_bounds__(512) void k_sscan(const int* __restrict__ bsum,
                                               int* __restrict__ bofs) {
    __shared__ int s[512];
    int tid = threadIdx.x;
    s[tid] = (tid < SCAN_B) ? bsum[tid] : 0;
    __syncthreads();
    #pragma unroll
    for (int off = 1; off < 512; off <<= 1) {
        int v = (tid >= off) ? s[tid - off] : 0;
        __syncthreads();
        s[tid] += v;
        __syncthreads();
    }
    if (tid < SCAN_B) bofs[tid] = (tid > 0) ? s[tid - 1] : 0;
}

// ---------- pass 3: intra-block scan + offset -> row_ptr/cursor/dinv ----------
__global__ __launch_bounds__(256) void k_apply(const int* __restrict__ cnt,
                                               const int* __restrict__ bofs,
                                               int* __restrict__ row_ptr,
                                               int* __restrict__ cursor,
                                               float* __restrict__ dinv) {
    __shared__ int s[256];
    int i = blockIdx.x * 256 + threadIdx.x;
    int v = (i < NN) ? cnt[i] : 0;
    s[threadIdx.x] = v;
    __syncthreads();
    #pragma unroll
    for (int off = 1; off < 256; off <<= 1) {
        int t = (threadIdx.x >= off) ? s[threadIdx.x - off] : 0;
        __syncthreads();
        s[threadIdx.x] += t;
        __syncthreads();
    }
    if (i < NN) {
        int incl = s[threadIdx.x] + bofs[blockIdx.x];
        int excl = incl - v;
        row_ptr[i] = excl;
        cursor[i] = excl;
        dinv[i] = rsqrtf((float)v + 1e-7f);
        if (i == NN - 1) row_ptr[NN] = incl;
    }
}

// ---------- XCD-range-partitioned scatter into CSR adjacency ----------
// (R0: WRITE_SIZE 127.5MB -> line-merged in one XCD's L2; total -278us.)
__global__ __launch_bounds__(256) void k_scatter2(const int* __restrict__ r,
                                                  const int* __restrict__ c,
                                                  int* __restrict__ cursor,
                                                  int* __restrict__ adj) {
    const int g = blockIdx.x;                 // 0..7
    const int lo = g * RANGE_SZ;
    int e = blockIdx.y * 256 + threadIdx.x;
    if (e >= EE) return;
    int a = r[e], b = c[e];
    if ((unsigned)a >= (unsigned)NU_ || (unsigned)b >= (unsigned)NI_) return; // defensive
    b += NU_;
    if ((unsigned)(a - lo) < (unsigned)RANGE_SZ) {
        int p = atomicAdd(&cursor[a], 1);
        adj[p] = b;
    }
    if ((unsigned)(b - lo) < (unsigned)RANGE_SZ) {
        int q = atomicAdd(&cursor[b], 1);
        adj[q] = a;
    }
}

// ---------- operand pre-scale: hbuf[i] = dinv[i]*(relu(x[i])+bias) ----------
// Also zeroes the pad row (index NN) of BOTH gather operands so the pulls
// can run fixed-16 inner loops with pad index = NN contributing zeros.
__global__ __launch_bounds__(256) void k_prep(const float* __restrict__ x,
                                              const float* __restrict__ bias,
                                              const float* __restrict__ dinv,
                                              float* __restrict__ hbuf,
                                              float* __restrict__ h2buf) {
    int i = blockIdx.x * 256 + threadIdx.x;   // float4 index, NN*DD/4 total
    int node = i >> 4;                        // 16 float4 per row
    float dv = dinv[node];
    const float4 xv = ((const float4*)x)[i];
    const float4 bv = ((const float4*)bias)[i & 15];
    float4 o;
    o.x = dv * (fmaxf(xv.x, 0.f) + bv.x);
    o.y = dv * (fmaxf(xv.y, 0.f) + bv.y);
    o.z = dv * (fmaxf(xv.z, 0.f) + bv.z);
    o.w = dv * (fmaxf(xv.w, 0.f) + bv.w);
    ((float4*)hbuf)[i] = o;
    if (blockIdx.x == 0 && threadIdx.x < 32) {
        float4 z = {0.f, 0.f, 0.f, 0.f};
        if (threadIdx.x < 16)
            ((float4*)&hbuf[(size_t)NN * DD])[threadIdx.x] = z;
        else
            ((float4*)&h2buf[(size_t)NN * DD])[threadIdx.x - 16] = z;
    }
}

// ---------- hop 1: edge = L h, pure gather-accumulate ----------
// Quarter-wave (16 lanes) per row; fixed-16 fully-unrolled inner loop
// (pad idx = NN -> zero row) keeps 16 dwordx4 gathers in flight.
// Writes out_e = dr*acc (required output) and h2buf = dr^2*acc (pre-scaled
// operand for hop 2 -> hop 2 needs NO per-neighbor dinv gather or shfl).
__global__ __launch_bounds__(256) void k_pullA(const int* __restrict__ row_ptr,
                                               const int* __restrict__ adj,
                                               const float* __restrict__ dinv,
                                               const float* __restrict__ hbuf,
                                               float* __restrict__ out_e,
                                               float* __restrict__ h2buf) {
    const int wave = threadIdx.x >> 6;
    const int lane = threadIdx.x & 63;
    const int sub  = lane >> 4;
    const int l16  = lane & 15;
    const int row  = (blockIdx.x * 4 + wave) * 4 + sub;   // NN%16==0
    const int start = row_ptr[row];
    const int end   = row_ptr[row + 1];
    float4 a0 = {0,0,0,0}, a1 = {0,0,0,0}, a2 = {0,0,0,0}, a3 = {0,0,0,0};
    for (int base = start; base < end; base += 16) {
        int t = base + l16;
        int idx = (t < end) ? adj[t] : NN;
        #pragma unroll
        for (int j = 0; j < 16; j++) {
            int nbr = __shfl(idx, (sub << 4) | j);
            const float4 hv = *(const float4*)&hbuf[(size_t)nbr * DD + l16 * 4];
            float4* ac = (j & 2) ? ((j & 1) ? &a3 : &a2) : ((j & 1) ? &a1 : &a0);
            ac->x += hv.x; ac->y += hv.y; ac->z += hv.z; ac->w += hv.w;
        }
    }
    float4 acc = {a0.x + a1.x + a2.x + a3.x, a0.y + a1.y + a2.y + a3.y,
                  a0.z + a1.z + a2.z + a3.z, a0.w + a1.w + a2.w + a3.w};
    const float dr = dinv[row];
    float4 e = {dr * acc.x, dr * acc.y, dr * acc.z, dr * acc.w};
    *(float4*)&out_e[(size_t)row * DD + l16 * 4] = e;
    float4 e2 = {dr * e.x, dr * e.y, dr * e.z, dr * e.w};
    *(float4*)&h2buf[(size_t)row * DD + l16 * 4] = e2;
}

// ---------- hop 2: node = L edge, same pure gather structure ----------
__global__ __launch_bounds__(256) void k_pullB(const int* __restrict__ row_ptr,
                                               const int* __restrict__ adj,
                                               const float* __restrict__ dinv,
                                               const float* __restrict__ h2buf,
                                               float* __restrict__ out_n) {
    const int wave = threadIdx.x >> 6;
    const int lane = threadIdx.x & 63;
    const int sub  = lane >> 4;
    const int l16  = lane & 15;
    const int row  = (blockIdx.x * 4 + wave) * 4 + sub;
    const int start = row_ptr[row];
    const int end   = row_ptr[row + 1];
    float4 a0 = {0,0,0,0}, a1 = {0,0,0,0}, a2 = {0,0,0,0}, a3 = {0,0,0,0};
    for (int base = start; base < end; base += 16) {
        int t = base + l16;
        int idx = (t < end) ? adj[t] : NN;
        #pragma unroll
        for (int j = 0; j < 16; j++) {
            int nbr = __shfl(idx, (sub << 4) | j);
            const float4 hv = *(const float4*)&h2buf[(size_t)nbr * DD + l16 * 4];
            float4* ac = (j & 2) ? ((j & 1) ? &a3 : &a2) : ((j & 1) ? &a1 : &a0);
            ac->x += hv.x; ac->y += hv.y; ac->z += hv.z; ac->w += hv.w;
        }
    }
    float4 acc = {a0.x + a1.x + a2.x + a3.x, a0.y + a1.y + a2.y + a3.y,
                  a0.z + a1.z + a2.z + a3.z, a0.w + a1.w + a2.w + a3.w};
    const float dr = dinv[row];
    float4 o = {dr * acc.x, dr * acc.y, dr * acc.z, dr * acc.w};
    *(float4*)&out_n[(size_t)row * DD + l16 * 4] = o;
}

// ---------- fused: softmax(node) -> fc1 -> fusion gate -> x_new ----------
#define BC(v, d) __uint_as_float(__builtin_amdgcn_readlane(__float_as_uint(v), (d)))

__global__ __launch_bounds__(256) void k_row(
    const float* __restrict__ node, const float* __restrict__ xsrc,
    const float* __restrict__ fc1W, const float* __restrict__ fusW,
    const float* __restrict__ l1b, const float* __restrict__ l2w,
    const float* __restrict__ l2b, float* __restrict__ out_nodes) {
    const int wave = threadIdx.x >> 6;
    const int lane = threadIdx.x & 63;

    float wf[DD], wu[DD];
    #pragma unroll
    for (int d = 0; d < DD; d += 4) {
        *(float4*)&wf[d] = *(const float4*)&fc1W[(size_t)lane * DD + d];
        *(float4*)&wu[d] = *(const float4*)&fusW[(size_t)lane * DD + d];
    }
    const float b1v = l1b[lane];
    const float l2v = l2w[lane];
    const float b2v = l2b[0];

    for (int row = blockIdx.x * 4 + wave; row < NN; row += gridDim.x * 4) {
        const size_t base = (size_t)row * DD + lane;
        float v = node[base];
        // --- softmax over D=64 ---
        float m = v;
        #pragma unroll
        for (int s = 1; s < 64; s <<= 1) m = fmaxf(m, __shfl_xor(m, s));
        float ev = __expf(v - m);
        float sum = ev;
        #pragma unroll
        for (int s = 1; s < 64; s <<= 1) sum += __shfl_xor(sum, s);
        float sm = ev / sum;
        // --- fc1 ---
        float n0 = 0, n1 = 0, n2 = 0, n3 = 0;
        #pragma unroll
        for (int d = 0; d < DD; d += 4) {
            n0 = fmaf(BC(sm, d),     wf[d],     n0);
            n1 = fmaf(BC(sm, d + 1), wf[d + 1], n1);
            n2 = fmaf(BC(sm, d + 2), wf[d + 2], n2);
            n3 = fmaf(BC(sm, d + 3), wf[d + 3], n3);
        }
        float nf = (n0 + n1) + (n2 + n3);
        float xc = xsrc[base];
        // --- fusion branch: xc ---
        float a0 = 0, a1 = 0, a2 = 0, a3 = 0;
        #pragma unroll
        for (int d = 0; d < DD; d += 4) {
            a0 = fmaf(BC(xc, d),     wu[d],     a0);
            a1 = fmaf(BC(xc, d + 1), wu[d + 1], a1);
            a2 = fmaf(BC(xc, d + 2), wu[d + 2], a2);
            a3 = fmaf(BC(xc, d + 3), wu[d + 3], a3);
        }
        float tt = tanhf(((a0 + a1) + (a2 + a3)) + b1v);
        float p = tt * l2v;
        #pragma unroll
        for (int s = 1; s < 64; s <<= 1) p += __shfl_xor(p, s);
        float s_x = p + b2v;
        // --- fusion branch: nf ---
        a0 = 0; a1 = 0; a2 = 0; a3 = 0;
        #pragma unroll
        for (int d = 0; d < DD; d += 4) {
            a0 = fmaf(BC(nf, d),     wu[d],     a0);
            a1 = fmaf(BC(nf, d + 1), wu[d + 1], a1);
            a2 = fmaf(BC(nf, d + 2), wu[d + 2], a2);
            a3 = fmaf(BC(nf, d + 3), wu[d + 3], a3);
        }
        tt = tanhf(((a0 + a1) + (a2 + a3)) + b1v);
        p = tt * l2v;
        #pragma unroll
        for (int s = 1; s < 64; s <<= 1) p += __shfl_xor(p, s);
        float s_n = p + b2v;
        // --- gate + blend ---
        float mm = fmaxf(s_x, s_n);
        float e0 = __expf(s_x - mm), e1 = __expf(s_n - mm);
        float inv = 1.0f / (e0 + e1);
        float xn = (e0 * xc + e1 * nf) * inv;
        out_nodes[base] = xn;
    }
}

extern "C" void kernel_launch(void* const* d_in, const int* in_sizes, int n_in,
                              void* d_out, int out_size, void* d_ws, size_t ws_size,
                              hipStream_t stream) {
    const float* x    = (const float*)d_in[0];
    const float* b1   = (const float*)d_in[1];  // hgc1_bias
    const float* fc1W = (const float*)d_in[2];
    const float* fusW = (const float*)d_in[3];  // fus_l1_W
    const float* l1b  = (const float*)d_in[4];
    const float* l2w  = (const float*)d_in[5];
    const float* l2b  = (const float*)d_in[6];
    const int* rows = (const int*)d_in[7];
    const int* cols = (const int*)d_in[8];
    float* out = (float*)d_out;

    const int ND = NN * DD;  // 6,400,000

    // workspace layout (~61 MB): gather operands first (16B aligned)
    float* hbuf    = (float*)d_ws;               // (NN+1)*DD
    float* h2buf   = hbuf + (size_t)(NN + 1) * DD;
    float* dinv    = h2buf + (size_t)(NN + 1) * DD;  // NN
    int*   cnt     = (int*)(dinv + NN);          // NN
    int*   row_ptr = cnt + NN;                   // NN+1
    int*   cursor  = row_ptr + NN + 1;           // NN
    int*   bsum    = cursor + NN;                // SCAN_B
    int*   bofs    = bsum + SCAN_B;              // SCAN_B
    int*   adj     = bofs + SCAN_B;              // 2*EE

    for (int k = 0; k < KK; k++) {
        const int* r = rows + (size_t)k * EE;
        const int* c = cols + (size_t)k * EE;
        const float* xk = (k == 0) ? x : out + (size_t)(k - 1) * ND;  // carry
        float* out_n = out + (size_t)k * ND;         // nodes[k] slot
        float* out_e = out + (size_t)(KK + k) * ND;  // edges[k] slot

        // --- CSR build (parallel scan) ---
        hipMemsetAsync(cnt, 0, NN * sizeof(int), stream);
        k_hist<<<(EE + 255) / 256, 256, 0, stream>>>(r, c, cnt);
        k_bsum<<<SCAN_B, 256, 0, stream>>>(cnt, bsum);
        k_sscan<<<1, 512, 0, stream>>>(bsum, bofs);
        k_apply<<<SCAN_B, 256, 0, stream>>>(cnt, bofs, row_ptr, cursor, dinv);
        {
            dim3 g(P_RANGES, (EE + 255) / 256);
            k_scatter2<<<g, 256, 0, stream>>>(r, c, cursor, adj);
        }

        // pre-scaled operand hbuf = dinv*(relu(xk)+bias), pad rows zeroed
        k_prep<<<ND / 4 / 256, 256, 0, stream>>>(xk, b1, dinv, hbuf, h2buf);

        // edge = L h  (writes edges[k] and pre-scaled hop-2 operand)
        k_pullA<<<NN / 16, 256, 0, stream>>>(row_ptr, adj, dinv, hbuf, out_e, h2buf);

        // node = L edge
        k_pullB<<<NN / 16, 256, 0, stream>>>(row_ptr, adj, dinv, h2buf, out_n);

        // softmax -> fc1 -> fusion gate; x_new in place into nodes[k]
        k_row<<<1024, 256, 0, stream>>>(out_n, xk, fc1W, fusW, l1b, l2w, l2b, out_n);
    }
}